// Round 11
// baseline (418.893 us; speedup 1.0000x reference)
//
#include <hip/hip_runtime.h>
#include <hip/hip_bf16.h>
#include <math.h>

// Problem constants
#define S_LEN   2048
#define BATCH   4
#define DMODEL  1024
#define NHEAD   16
#define DHEAD   64
#define MROWS   (S_LEN * BATCH)   // 8192 rows in flattened (s,b) order

typedef __bf16 bf16;
typedef __bf16 bf16x8 __attribute__((ext_vector_type(8)));
typedef __bf16 bf16x4 __attribute__((ext_vector_type(4)));
typedef short  short4_t __attribute__((ext_vector_type(4)));
typedef float  f32x4  __attribute__((ext_vector_type(4)));

#define LOG2E 1.4426950408889634f

// address-space casts for global_load_lds (direct global->LDS DMA)
#define AS1C(p) (const __attribute__((address_space(1))) void*)(p)
#define AS3(p)  (__attribute__((address_space(3))) void*)(p)

// Packed-layout definitions (per (b,h) slab of 128 key-tiles x 1024 elems):
//  Kp: tile T (16 keys): elem[T*1024 + c*512 + (s%16 + 16*(u>>3))*8 + (u&7)]
//      = K[s][dh], c=dh>>5, u=dh&31.  Wave fragment kf_c = 16B at lane*16.
//  Vp: tile T, d-tile dt: elem[T*1024 + dt*256 + (dh%16 + 16*((s%16)>>2))*4
//      + (s%16)&3] = V[s][dh].  Wave fragment va[dt] = 8B at lane*8.

// ---------------------------------------------------------------------------
// R6: single fused cast kernel.  Group space: [0, NX8) = x -> xb; then 4
// weight segments of NW8 groups (Wq,Wk,Wv -> stacked wqkv; Wo -> wob).
// ---------------------------------------------------------------------------
__global__ __launch_bounds__(256) void cast_all(const float* __restrict__ x,
                                                const float* __restrict__ wq,
                                                const float* __restrict__ wk,
                                                const float* __restrict__ wv,
                                                const float* __restrict__ wo,
                                                bf16* __restrict__ xb,
                                                bf16* __restrict__ wqkv,
                                                bf16* __restrict__ wob) {
    const int i = blockIdx.x * 256 + threadIdx.x;
    constexpr int NX8 = MROWS * DMODEL / 8;    // 2^20
    constexpr int NW8 = DMODEL * DMODEL / 8;   // 2^17
    const float* src;
    bf16* dst;
    int k;
    if (i < NX8) {
        src = x; dst = xb; k = i;
    } else {
        const int j   = i - NX8;
        const int seg = j >> 17;          // j / NW8
        k = j & (NW8 - 1);
        if (seg == 0)      { src = wq; dst = wqkv; }
        else if (seg == 1) { src = wk; dst = wqkv + (size_t)DMODEL * DMODEL; }
        else if (seg == 2) { src = wv; dst = wqkv + (size_t)2 * DMODEL * DMODEL; }
        else               { src = wo; dst = wob; }
    }
    const float4* p = (const float4*)src;
    float4 a = p[(size_t)k * 2], b = p[(size_t)k * 2 + 1];
    bf16x8 o;
    o[0] = (bf16)a.x; o[1] = (bf16)a.y; o[2] = (bf16)a.z; o[3] = (bf16)a.w;
    o[4] = (bf16)b.x; o[5] = (bf16)b.y; o[6] = (bf16)b.z; o[7] = (bf16)b.w;
    *(bf16x8*)(dst + (size_t)k * 8) = o;
}

// ---------------------------------------------------------------------------
// R7 qkv GEMM: 128x128 tile, BK=32, 8 waves (512 thr) as 2M x 4N, per-wave
// 64x32 (acc[4][2]).  3-buffer LDS 48KB -> 3 blocks/CU (launch_bounds(512,6)),
// grid (24,64)=1536 = 3 even rounds of 512.  Depth-2 counted-vmcnt(2)
// pipeline, XOR bank-spread swizzle both sides, setprio.  FROZEN (best).
// ---------------------------------------------------------------------------
__global__ __launch_bounds__(512, 6) void qkv_gemm(const bf16* __restrict__ A,
                                                   const bf16* __restrict__ W,
                                                   const float* __restrict__ bq,
                                                   const float* __restrict__ bk,
                                                   const float* __restrict__ bv,
                                                   const float* __restrict__ beta,
                                                   bf16* __restrict__ Qo,
                                                   bf16* __restrict__ Kp,
                                                   bf16* __restrict__ Vp) {
    constexpr int BK = 32;
    constexpr int NT = DMODEL / BK;   // 32
    __shared__ __align__(16) bf16 sA[3][128 * BK];   // 3 x 8 KB
    __shared__ __align__(16) bf16 sB[3][128 * BK];   // 3 x 8 KB
    const int t    = threadIdx.x;
    const int lane = t & 63;
    const int wave = t >> 6;     // 0..7
    const int wr   = wave >> 2;  // 0..1 (row half: 64 rows)
    const int wc   = wave & 3;   // 0..3 (col quarter: 32 cols)
    const int lq   = lane & 15;
    const int lg   = lane >> 4;
    const int bn   = blockIdx.x * 128;   // [0, 3072)
    const int bm   = blockIdx.y * 128;

    const int schunk = (lane & 3) ^ ((lane >> 3) & 3);
    const bf16* ApS = A + (size_t)(bm + wave * 16 + (lane >> 2)) * DMODEL + schunk * 8;
    const bf16* WpS = W + (size_t)(bn + wave * 16 + (lane >> 2)) * DMODEL + schunk * 8;
    const int koff = (lg ^ ((lq >> 1) & 3)) * 8;
    f32x4 acc[4][2] = {};

#define QSTG(si_, ko_)                                                                   \
    __builtin_amdgcn_global_load_lds(AS1C(ApS + (ko_)), AS3(&sA[si_][wave * 512]), 16, 0, 0); \
    __builtin_amdgcn_global_load_lds(AS1C(WpS + (ko_)), AS3(&sB[si_][wave * 512]), 16, 0, 0);

    QSTG(0, 0)
    QSTG(1, BK)
    asm volatile("s_waitcnt vmcnt(2)\n\ts_barrier" ::: "memory");

    int bi = 0, si = 2, st = 2;
    for (int tt = 0; tt < NT; ++tt) {
        QSTG(si, (size_t)st * BK)   // stage tile tt+2 (wraps to junk at tail)
        const bf16* At = sA[bi];
        const bf16* Bt = sB[bi];
        bf16x8 bf0 = *(const bf16x8*)&Bt[(wc * 32 +      lq) * BK + koff];
        bf16x8 bf1 = *(const bf16x8*)&Bt[(wc * 32 + 16 + lq) * BK + koff];
        bf16x8 af[4];
#pragma unroll
        for (int mt = 0; mt < 4; mt++)
            af[mt] = *(const bf16x8*)&At[(wr * 64 + mt * 16 + lq) * BK + koff];
        __builtin_amdgcn_s_setprio(1);
#pragma unroll
        for (int mt = 0; mt < 4; mt++) {
            acc[mt][0] = __builtin_amdgcn_mfma_f32_16x16x32_bf16(af[mt], bf0, acc[mt][0], 0, 0, 0);
            acc[mt][1] = __builtin_amdgcn_mfma_f32_16x16x32_bf16(af[mt], bf1, acc[mt][1], 0, 0, 0);
        }
        __builtin_amdgcn_s_setprio(0);
        asm volatile("s_waitcnt vmcnt(2)\n\ts_barrier" ::: "memory");
        bi = (bi == 2) ? 0 : bi + 1;
        si = (si == 2) ? 0 : si + 1;
        st = (st == NT - 1) ? 0 : st + 1;
    }
#undef QSTG

    const int seg = blockIdx.x >> 3;         // 0=Q, 1=K, 2=V (wave-uniform)
    const int bnl = (blockIdx.x & 7) * 128;  // col base within segment
    const float* bias = (seg == 0) ? bq : (seg == 1) ? bk : bv;

    if (seg == 0) {
#pragma unroll
        for (int nt = 0; nt < 2; nt++) {
            const int col = bnl + wc * 32 + nt * 16 + lq;
            const float bvv = bias[col];
            const float sc = LOG2E / (__expf(beta[col >> 6]) * 8.0f);
#pragma unroll
            for (int mt = 0; mt < 4; mt++) {
                const int row = bm + wr * 64 + mt * 16 + lg * 4;
#pragma unroll
                for (int r = 0; r < 4; r++) {
                    float v = (acc[mt][nt][r] + bvv) * sc;
                    Qo[(size_t)(row + r) * DMODEL + col] = (bf16)v;
                }
            }
        }
    } else {
        bf16* out = (seg == 1) ? Kp : Vp;
#pragma unroll
        for (int mt = 0; mt < 4; mt++) {
            const int F   = bm + wr * 64 + mt * 16;
            const int S0X = F >> 2;              // s of (lg=0): s = S0X + lg
            const int T   = S0X >> 4;            // key-tile index s/16
            const int sl  = (S0X & 15) + lg;     // s within tile (S0X%4==0)
#pragma unroll
            for (int nt = 0; nt < 2; nt++) {
                const int col = bnl + wc * 32 + nt * 16 + lq;
                const int h   = col >> 6;
                const int dh  = col & 63;
                const float bvv = bias[col];
#pragma unroll
                for (int r = 0; r < 4; r++) {   // r = batch b
                    float v = acc[mt][nt][r] + bvv;
                    size_t addr;
                    if (seg == 1) {   // Kp: c=dh>>5, u=dh&31
                        addr = ((size_t)((r * 16 + h) * 128 + T)) * 1024
                             + (dh >> 5) * 512
                             + (sl + 16 * ((dh >> 3) & 3)) * 8
                             + (dh & 7);
                    } else {          // Vp: dt=dh>>4
                        addr = ((size_t)((r * 16 + h) * 128 + T)) * 1024
                             + (dh >> 4) * 256 + ((dh & 15) + 16 * (sl >> 2)) * 4
                             + (sl & 3);
                    }
                    out[addr] = (bf16)v;
                }
            }
        }
    }
}

// ---------------------------------------------------------------------------
// R10 output projection: R5 structure + XCD-chunked bijective swizzle.
// FROZEN.
// ---------------------------------------------------------------------------
__global__ __launch_bounds__(256, 3) void gemm_out(const bf16* __restrict__ A,
                                                   const bf16* __restrict__ W,
                                                   const float* __restrict__ bias,
                                                   float* __restrict__ C) {
    constexpr int BK = 32;
    constexpr int NTILES = DMODEL / BK;   // 32
    __shared__ __align__(16) bf16 sA[3][128 * BK];   // 24 KB
    __shared__ __align__(16) bf16 sB[3][128 * BK];   // 24 KB

    const int t    = threadIdx.x;
    const int lane = t & 63;
    const int wave = t >> 6;     // 0..3
    const int wr   = wave >> 1;  // 0..1
    const int wc   = wave & 1;   // 0..1
    const int lq   = lane & 15;
    const int lg   = lane >> 4;

    // XCD-chunked bijective swizzle (512 blocks, 8 XCDs, 64 ids per XCD)
    const int bid = (int)blockIdx.x + 8 * (int)blockIdx.y;
    const int swz = (bid & 7) * 64 + (bid >> 3);
    const int bn  = (swz & 7) * 128;
    const int bm  = (swz >> 3) * 128;

    const int schunk = (lane & 3) ^ ((lane >> 3) & 3);
    const bf16* ApS = A + (size_t)(bm + wave * 32 + (lane >> 2)) * DMODEL + schunk * 8;
    const bf16* WpS = W + (size_t)(bn + wave * 32 + (lane >> 2)) * DMODEL + schunk * 8;
    const int koff = (lg ^ ((lq >> 1) & 3)) * 8;

    f32x4 acc[4][4] = {};

#define OSTAGE(si_, ko_)                                                                              \
    __builtin_amdgcn_global_load_lds(AS1C(ApS + (ko_)),               AS3(&sA[si_][(wave*32 +  0)*BK]), 16,0,0); \
    __builtin_amdgcn_global_load_lds(AS1C(ApS + 16*DMODEL + (ko_)),   AS3(&sA[si_][(wave*32 + 16)*BK]), 16,0,0); \
    __builtin_amdgcn_global_load_lds(AS1C(WpS + (ko_)),               AS3(&sB[si_][(wave*32 +  0)*BK]), 16,0,0); \
    __builtin_amdgcn_global_load_lds(AS1C(WpS + 16*DMODEL + (ko_)),   AS3(&sB[si_][(wave*32 + 16)*BK]), 16,0,0);

    OSTAGE(0, 0)
    OSTAGE(1, BK)
    asm volatile("s_waitcnt vmcnt(4)\n\ts_barrier" ::: "memory");

    int bi = 0, si = 2, st = 2;
    for (int tt = 0; tt < NTILES; ++tt) {
        OSTAGE(si, (size_t)st * BK)
        const bf16* At = sA[bi];
        const bf16* Bt = sB[bi];
        bf16x8 bfr[4], af[4];
#pragma unroll
        for (int nt = 0; nt < 4; nt++)
            bfr[nt] = *(const bf16x8*)&Bt[(wc * 64 + nt * 16 + lq) * BK + koff];
#pragma unroll
        for (int mt = 0; mt < 4; mt++)
            af[mt] = *(const bf16x8*)&At[(wr * 64 + mt * 16 + lq) * BK + koff];
        __builtin_amdgcn_s_setprio(1);
#pragma unroll
        for (int mt = 0; mt < 4; mt++)
#pragma unroll
            for (int nt = 0; nt < 4; nt++)
                acc[mt][nt] = __builtin_amdgcn_mfma_f32_16x16x32_bf16(af[mt], bfr[nt], acc[mt][nt], 0, 0, 0);
        __builtin_amdgcn_s_setprio(0);
        asm volatile("s_waitcnt vmcnt(4)\n\ts_barrier" ::: "memory");
        bi = (bi == 2) ? 0 : bi + 1;
        si = (si == 2) ? 0 : si + 1;
        st = (st == NTILES - 1) ? 0 : st + 1;
    }
#undef OSTAGE

#pragma unroll
    for (int nt = 0; nt < 4; nt++) {
        const int col = bn + wc * 64 + nt * 16 + lq;
        const float bvv = bias[col];
#pragma unroll
        for (int mt = 0; mt < 4; mt++) {
            const int row = bm + wr * 64 + mt * 16 + lg * 4;
#pragma unroll
            for (int r = 0; r < 4; r++)
                C[(size_t)(row + r) * DMODEL + col] = acc[mt][nt][r] + bvv;
        }
    }
}

// ---------------------------------------------------------------------------
// Flash attention, causal + zero-sink, keys-split waves — R11: Q-in-LDS
// register diet.
//
// Proven invariants (R8/R9 lessons), all PRESERVED:
//  (1) 1-deep register prefetch of K/V;
//  (2) keys-split: each wave loads a DISTINCT key-tile per iteration
//      (block streams K/V once);
//  (3) L2 working set small: no pairing -> resident 128 ids/XCD = 4 slabs
//      = 2 MB << 4 MB L2 (pairing at 4 blocks/CU would be exactly 4 MB =
//      the R8 thrash point);
//  (4) XCD-chunked bijective swizzle, heavy-first.
//
// R11 change: the loop-invariant Q fragments (32 VGPRs held all-kernel)
// move to LDS (8 KB tile, staged once via 2 global_load_lds with the
// proven both-sides XOR swizzle: physical 16B chunk p of row r holds
// logical chunk p^(r&7); reader 2-way bank aliasing = free).  Per
// iteration each wave re-reads its 8 fragments (8x ds_read_b128, 2 addr
// regs + offset immediates) as transients.  Reg budget ~60 VGPR + 64
// AGPR <= 128 -> 4 blocks/CU WITH prefetch (launch_bounds(256,4)); this
// was the binding constraint at R7's Occ 22.9%.
// ---------------------------------------------------------------------------
__global__ __launch_bounds__(256, 4) void attn_kernel(const bf16* __restrict__ Q,
                                                      const bf16* __restrict__ Kp,
                                                      const bf16* __restrict__ Vp,
                                                      bf16* __restrict__ O) {
    __shared__ __align__(16) float sO[64 * 65];   // 16640 B (epilogue only)
    __shared__ __align__(16) float sL[256];       // 1024 B
    __shared__ __align__(16) bf16  sQ[4096];      // 8 KB Q tile, XOR-swizzled

    const int t    = threadIdx.x;
    const int lane = t & 63;
    const int wave = t >> 6;
    const int lq = lane & 15;
    const int lg = lane >> 4;

    // ---- XCD-chunked swizzle (2048 blocks, 8 XCDs, 256 work-ids per XCD) ----
    const int bid = (int)blockIdx.x + 32 * ((int)blockIdx.y + 16 * (int)blockIdx.z);
    const int swz = (bid & 7) * 256 + (bid >> 3);
    const int qi  = 31 - (swz & 31);              // heavy tiles first per chunk
    const int h   = (swz >> 5) & 15;
    const int b   = swz >> 9;
    const int qb  = qi * 64;

    const bf16* Kb = Kp + (size_t)(b * NHEAD + h) * 131072;   // 128 tiles * 1024
    const bf16* Vb = Vp + (size_t)(b * NHEAD + h) * 131072;

    // ---- stage Q tile (64 rows x 64 cols bf16) into sQ, swizzled ----
    // Linear LDS dest (rule 21) + pre-swizzled global source: thread covers
    // row rw = call*32 + wave*8 + (lane>>3), physical chunk lane&7, whose
    // logical chunk is (lane&7) ^ (rw&7) = (lane&7) ^ (lane>>3).
    {
        const int rw  = wave * 8 + (lane >> 3);
        const int lch = (lane & 7) ^ (lane >> 3);
        const bf16* q0 = Q + ((size_t)(qb + rw) * BATCH + b) * DMODEL + h * DHEAD + lch * 8;
        const bf16* q1 = Q + ((size_t)(qb + 32 + rw) * BATCH + b) * DMODEL + h * DHEAD + lch * 8;
        __builtin_amdgcn_global_load_lds(AS1C(q0), AS3(&sQ[wave * 512]),        16, 0, 0);
        __builtin_amdgcn_global_load_lds(AS1C(q1), AS3(&sQ[2048 + wave * 512]), 16, 0, 0);
    }

    // loop-invariant swizzled fragment offsets (elements); nt adds 1024/tile
    // reader: row R = nt*16+lq, logical chunk c = kc*4+lg, physical p = c^(lq&7)
    const int a0 = lq * 64 + ((0 + lg) ^ (lq & 7)) * 8;   // kc=0
    const int a1 = lq * 64 + ((4 + lg) ^ (lq & 7)) * 8;   // kc=1

    f32x4 o_acc[4][4] = {};   // o_acc[dt][nt][r]: O^T row d=dt*16+lg*4+r, col q=nt*16+lq
    float l_lane[4] = {0.f, 0.f, 0.f, 0.f};

    // tile-0 K/V current regs (keys-split: this wave's tile = kt*4+wave)
    bf16x8 kc0 = *(const bf16x8*)(Kb + (size_t)wave * 1024 + lane * 8);
    bf16x8 kc1 = *(const bf16x8*)(Kb + (size_t)wave * 1024 + 512 + lane * 8);
    bf16x4 vc0 = *(const bf16x4*)(Vb + (size_t)wave * 1024 +   0 + lane * 4);
    bf16x4 vc1 = *(const bf16x4*)(Vb + (size_t)wave * 1024 + 256 + lane * 4);
    bf16x4 vc2 = *(const bf16x4*)(Vb + (size_t)wave * 1024 + 512 + lane * 4);
    bf16x4 vc3 = *(const bf16x4*)(Vb + (size_t)wave * 1024 + 768 + lane * 4);

    // sQ (and tile-0 K/V) ready for all waves
    asm volatile("s_waitcnt vmcnt(0)\n\ts_barrier" ::: "memory");

    for (int kt = 0; kt <= qi; kt++) {
        // prefetch next tile (wraps to tile 0 on last iter, unused)
        const int tn = ((kt < qi) ? (kt + 1) : 0) * 4 + wave;
        const bf16* Kn = Kb + (size_t)tn * 1024;
        const bf16* Vn = Vb + (size_t)tn * 1024;
        bf16x8 kn0 = *(const bf16x8*)(Kn + lane * 8);
        bf16x8 kn1 = *(const bf16x8*)(Kn + 512 + lane * 8);
        bf16x4 vn0 = *(const bf16x4*)(Vn +   0 + lane * 4);
        bf16x4 vn1 = *(const bf16x4*)(Vn + 256 + lane * 4);
        bf16x4 vn2 = *(const bf16x4*)(Vn + 512 + lane * 4);
        bf16x4 vn3 = *(const bf16x4*)(Vn + 768 + lane * 4);

        // St[key][q]: this wave's 16 keys x 64 q (A = K rows, B = Q rows
        // re-read from sQ per iteration; transient regs)
        f32x4 st[4];
        __builtin_amdgcn_s_setprio(1);
#pragma unroll
        for (int nt = 0; nt < 4; nt++) {
            bf16x8 q0 = *(const bf16x8*)&sQ[nt * 1024 + a0];
            bf16x8 q1 = *(const bf16x8*)&sQ[nt * 1024 + a1];
            f32x4 a = {};
            a = __builtin_amdgcn_mfma_f32_16x16x32_bf16(kc0, q0, a, 0, 0, 0);
            a = __builtin_amdgcn_mfma_f32_16x16x32_bf16(kc1, q1, a, 0, 0, 0);
            st[nt] = a;
        }
        __builtin_amdgcn_s_setprio(0);

        // causal mask on the diagonal tile: key_local > q_local -> -inf
        if (kt == qi) {
#pragma unroll
            for (int nt = 0; nt < 4; nt++)
#pragma unroll
                for (int r = 0; r < 4; r++)
                    if (wave * 16 + lg * 4 + r > nt * 16 + lq) st[nt][r] = -1e30f;
        }

        // P^T = exp2(St) (scores pre-scaled by log2e), pack to bf16, track l
        short4_t pf[4];
#pragma unroll
        for (int nt = 0; nt < 4; nt++) {
            float p0 = __builtin_amdgcn_exp2f(st[nt][0]);
            float p1 = __builtin_amdgcn_exp2f(st[nt][1]);
            float p2 = __builtin_amdgcn_exp2f(st[nt][2]);
            float p3 = __builtin_amdgcn_exp2f(st[nt][3]);
            l_lane[nt] += (p0 + p1) + (p2 + p3);
            bf16x4 pv;
            pv[0] = (bf16)p0; pv[1] = (bf16)p1; pv[2] = (bf16)p2; pv[3] = (bf16)p3;
            pf[nt] = __builtin_bit_cast(short4_t, pv);
        }

        // O^T += Vt(d x key16) * P^T   via mfma_f32_16x16x16_bf16
        short4_t va0 = __builtin_bit_cast(short4_t, vc0);
        short4_t va1 = __builtin_bit_cast(short4_t, vc1);
        short4_t va2 = __builtin_bit_cast(short4_t, vc2);
        short4_t va3 = __builtin_bit_cast(short4_t, vc3);
        __builtin_amdgcn_s_setprio(1);
#pragma unroll
        for (int nt = 0; nt < 4; nt++) {
            o_acc[0][nt] = __builtin_amdgcn_mfma_f32_16x16x16bf16_1k(va0, pf[nt], o_acc[0][nt], 0, 0, 0);
            o_acc[1][nt] = __builtin_amdgcn_mfma_f32_16x16x16bf16_1k(va1, pf[nt], o_acc[1][nt], 0, 0, 0);
            o_acc[2][nt] = __builtin_amdgcn_mfma_f32_16x16x16bf16_1k(va2, pf[nt], o_acc[2][nt], 0, 0, 0);
            o_acc[3][nt] = __builtin_amdgcn_mfma_f32_16x16x16bf16_1k(va3, pf[nt], o_acc[3][nt], 0, 0, 0);
        }
        __builtin_amdgcn_s_setprio(0);

        kc0 = kn0; kc1 = kn1;
        vc0 = vn0; vc1 = vn1; vc2 = vn2; vc3 = vn3;
    }

    // ---------------- epilogue: cross-wave reduction ----------------
#pragma unroll
    for (int nt = 0; nt < 4; nt++) {
        float v = l_lane[nt];
        v += __shfl_xor(v, 16);
        v += __shfl_xor(v, 32);
        if (lg == 0) sL[wave * 64 + nt * 16 + lq] = v;
    }

    // O^T reduction rounds. Round rd: wave w handles slice dt=(w+rd)&3
#pragma unroll
    for (int rd = 0; rd < 4; rd++) {
#pragma unroll
        for (int dtc = 0; dtc < 4; dtc++) {
            if (((wave + rd) & 3) == dtc) {
                if (rd == 0) {
#pragma unroll
                    for (int nt = 0; nt < 4; nt++)
#pragma unroll
                        for (int r = 0; r < 4; r++)
                            sO[(dtc * 16 + lg * 4 + r) * 65 + nt * 16 + lq] = o_acc[dtc][nt][r];
                } else {
#pragma unroll
                    for (int nt = 0; nt < 4; nt++)
#pragma unroll
                        for (int r = 0; r < 4; r++)
                            sO[(dtc * 16 + lg * 4 + r) * 65 + nt * 16 + lq] += o_acc[dtc][nt][r];
                }
            }
        }
        __syncthreads();
    }

    // final: wave stores dt=wave slice of O = O^T / l  (sink adds 1 to l)
    const int dt = wave;
    float rec[4];
#pragma unroll
    for (int nt = 0; nt < 4; nt++) {
        float lt = 1.0f + sL[nt * 16 + lq] + sL[64 + nt * 16 + lq]
                 + sL[128 + nt * 16 + lq] + sL[192 + nt * 16 + lq];
        rec[nt] = 1.0f / lt;
    }
#pragma unroll
    for (int nt = 0; nt < 4; nt++) {
        bf16x4 ov;
#pragma unroll
        for (int r = 0; r < 4; r++)
            ov[r] = (bf16)(sO[(dt * 16 + lg * 4 + r) * 65 + nt * 16 + lq] * rec[nt]);
        *(bf16x4*)&O[((size_t)(qb + nt * 16 + lq) * BATCH + b) * DMODEL + h * DHEAD + dt * 16 + lg * 4] = ov;
    }
}

// ---------------------------------------------------------------------------
extern "C" void kernel_launch(void* const* d_in, const int* in_sizes, int n_in,
                              void* d_out, int out_size, void* d_ws, size_t ws_size,
                              hipStream_t stream) {
    const float* x    = (const float*)d_in[0];
    // d_in[1] = attn_mask (pure causal -1e9; implemented structurally)
    const float* beta = (const float*)d_in[2];
    const float* Wq   = (const float*)d_in[3];
    const float* bq   = (const float*)d_in[4];
    const float* Wk   = (const float*)d_in[5];
    const float* bk   = (const float*)d_in[6];
    const float* Wv   = (const float*)d_in[7];
    const float* bv   = (const float*)d_in[8];
    const float* Wo   = (const float*)d_in[9];
    const float* bo   = (const float*)d_in[10];
    float* out = (float*)d_out;

    char* ws = (char*)d_ws;
    size_t off = 0;
    auto alloc = [&](size_t bytes) -> void* {
        void* p = ws + off;
        off += (bytes + 255) & ~(size_t)255;
        return p;
    };
    const size_t xbytes = (size_t)MROWS * DMODEL * sizeof(bf16);   // 16 MB
    const size_t wbytes = (size_t)DMODEL * DMODEL * sizeof(bf16);  // 2 MB
    bf16* xb   = (bf16*)alloc(xbytes);
    bf16* wqkv = (bf16*)alloc(3 * wbytes);   // stacked Wq/Wk/Wv
    bf16* wob  = (bf16*)alloc(wbytes);
    bf16* qws  = (bf16*)alloc(xbytes);
    bf16* kpb  = (bf16*)alloc(xbytes);   // packed K
    bf16* vpb  = (bf16*)alloc(xbytes);   // packed V
    bf16* aob  = (bf16*)alloc(xbytes);

    constexpr int NX8 = MROWS * DMODEL / 8;
    constexpr int NW8 = DMODEL * DMODEL / 8;
    cast_all<<<(NX8 + 4 * NW8) / 256, 256, 0, stream>>>(x, Wq, Wk, Wv, Wo, xb, wqkv, wob);

    dim3 qgrid(3 * DMODEL / 128, MROWS / 128);   // (24, 64) = 1536 blocks
    qkv_gemm<<<qgrid, 512, 0, stream>>>(xb, wqkv, bq, bk, bv, beta, qws, kpb, vpb);

    dim3 agrid(S_LEN / 64, NHEAD, BATCH);        // (32, 16, 4) = 2048 blocks
    attn_kernel<<<agrid, 256, 0, stream>>>(qws, kpb, vpb, aob);

    dim3 ogrid(DMODEL / 128, MROWS / 128);       // (8, 64) = 512 blocks
    gemm_out<<<ogrid, 256, 0, stream>>>(aob, wob, bo, out);
}

// Round 12
// 270.987 us; speedup vs baseline: 1.5458x; 1.5458x over previous
//
#include <hip/hip_runtime.h>
#include <hip/hip_bf16.h>
#include <math.h>

// Problem constants
#define S_LEN   2048
#define BATCH   4
#define DMODEL  1024
#define NHEAD   16
#define DHEAD   64
#define MROWS   (S_LEN * BATCH)   // 8192 rows in flattened (s,b) order

typedef __bf16 bf16;
typedef __bf16 bf16x8 __attribute__((ext_vector_type(8)));
typedef __bf16 bf16x4 __attribute__((ext_vector_type(4)));
typedef short  short4_t __attribute__((ext_vector_type(4)));
typedef float  f32x4  __attribute__((ext_vector_type(4)));

#define LOG2E 1.4426950408889634f

// address-space casts for global_load_lds (direct global->LDS DMA)
#define AS1C(p) (const __attribute__((address_space(1))) void*)(p)
#define AS3(p)  (__attribute__((address_space(3))) void*)(p)

// Packed-layout definitions (per (b,h) slab of 128 key-tiles x 1024 elems):
//  Kp: tile T (16 keys): elem[T*1024 + c*512 + (s%16 + 16*(u>>3))*8 + (u&7)]
//      = K[s][dh], c=dh>>5, u=dh&31.  Wave fragment kf_c = 16B at lane*16.
//  Vp: tile T, d-tile dt: elem[T*1024 + dt*256 + (dh%16 + 16*((s%16)>>2))*4
//      + (s%16)&3] = V[s][dh].  Wave fragment va[dt] = 8B at lane*8.

// ---------------------------------------------------------------------------
// R6: single fused cast kernel.  Group space: [0, NX8) = x -> xb; then 4
// weight segments of NW8 groups (Wq,Wk,Wv -> stacked wqkv; Wo -> wob).
// ---------------------------------------------------------------------------
__global__ __launch_bounds__(256) void cast_all(const float* __restrict__ x,
                                                const float* __restrict__ wq,
                                                const float* __restrict__ wk,
                                                const float* __restrict__ wv,
                                                const float* __restrict__ wo,
                                                bf16* __restrict__ xb,
                                                bf16* __restrict__ wqkv,
                                                bf16* __restrict__ wob) {
    const int i = blockIdx.x * 256 + threadIdx.x;
    constexpr int NX8 = MROWS * DMODEL / 8;    // 2^20
    constexpr int NW8 = DMODEL * DMODEL / 8;   // 2^17
    const float* src;
    bf16* dst;
    int k;
    if (i < NX8) {
        src = x; dst = xb; k = i;
    } else {
        const int j   = i - NX8;
        const int seg = j >> 17;          // j / NW8
        k = j & (NW8 - 1);
        if (seg == 0)      { src = wq; dst = wqkv; }
        else if (seg == 1) { src = wk; dst = wqkv + (size_t)DMODEL * DMODEL; }
        else if (seg == 2) { src = wv; dst = wqkv + (size_t)2 * DMODEL * DMODEL; }
        else               { src = wo; dst = wob; }
    }
    const float4* p = (const float4*)src;
    float4 a = p[(size_t)k * 2], b = p[(size_t)k * 2 + 1];
    bf16x8 o;
    o[0] = (bf16)a.x; o[1] = (bf16)a.y; o[2] = (bf16)a.z; o[3] = (bf16)a.w;
    o[4] = (bf16)b.x; o[5] = (bf16)b.y; o[6] = (bf16)b.z; o[7] = (bf16)b.w;
    *(bf16x8*)(dst + (size_t)k * 8) = o;
}

// ---------------------------------------------------------------------------
// R7 qkv GEMM: 128x128 tile, BK=32, 8 waves (512 thr) as 2M x 4N, per-wave
// 64x32 (acc[4][2]).  3-buffer LDS 48KB -> 3 blocks/CU (launch_bounds(512,6)),
// grid (24,64)=1536 = 3 even rounds of 512.  Depth-2 counted-vmcnt(2)
// pipeline, XOR bank-spread swizzle both sides, setprio.  FROZEN (best).
// ---------------------------------------------------------------------------
__global__ __launch_bounds__(512, 6) void qkv_gemm(const bf16* __restrict__ A,
                                                   const bf16* __restrict__ W,
                                                   const float* __restrict__ bq,
                                                   const float* __restrict__ bk,
                                                   const float* __restrict__ bv,
                                                   const float* __restrict__ beta,
                                                   bf16* __restrict__ Qo,
                                                   bf16* __restrict__ Kp,
                                                   bf16* __restrict__ Vp) {
    constexpr int BK = 32;
    constexpr int NT = DMODEL / BK;   // 32
    __shared__ __align__(16) bf16 sA[3][128 * BK];   // 3 x 8 KB
    __shared__ __align__(16) bf16 sB[3][128 * BK];   // 3 x 8 KB
    const int t    = threadIdx.x;
    const int lane = t & 63;
    const int wave = t >> 6;     // 0..7
    const int wr   = wave >> 2;  // 0..1 (row half: 64 rows)
    const int wc   = wave & 3;   // 0..3 (col quarter: 32 cols)
    const int lq   = lane & 15;
    const int lg   = lane >> 4;
    const int bn   = blockIdx.x * 128;   // [0, 3072)
    const int bm   = blockIdx.y * 128;

    const int schunk = (lane & 3) ^ ((lane >> 3) & 3);
    const bf16* ApS = A + (size_t)(bm + wave * 16 + (lane >> 2)) * DMODEL + schunk * 8;
    const bf16* WpS = W + (size_t)(bn + wave * 16 + (lane >> 2)) * DMODEL + schunk * 8;
    const int koff = (lg ^ ((lq >> 1) & 3)) * 8;
    f32x4 acc[4][2] = {};

#define QSTG(si_, ko_)                                                                   \
    __builtin_amdgcn_global_load_lds(AS1C(ApS + (ko_)), AS3(&sA[si_][wave * 512]), 16, 0, 0); \
    __builtin_amdgcn_global_load_lds(AS1C(WpS + (ko_)), AS3(&sB[si_][wave * 512]), 16, 0, 0);

    QSTG(0, 0)
    QSTG(1, BK)
    asm volatile("s_waitcnt vmcnt(2)\n\ts_barrier" ::: "memory");

    int bi = 0, si = 2, st = 2;
    for (int tt = 0; tt < NT; ++tt) {
        QSTG(si, (size_t)st * BK)   // stage tile tt+2 (wraps to junk at tail)
        const bf16* At = sA[bi];
        const bf16* Bt = sB[bi];
        bf16x8 bf0 = *(const bf16x8*)&Bt[(wc * 32 +      lq) * BK + koff];
        bf16x8 bf1 = *(const bf16x8*)&Bt[(wc * 32 + 16 + lq) * BK + koff];
        bf16x8 af[4];
#pragma unroll
        for (int mt = 0; mt < 4; mt++)
            af[mt] = *(const bf16x8*)&At[(wr * 64 + mt * 16 + lq) * BK + koff];
        __builtin_amdgcn_s_setprio(1);
#pragma unroll
        for (int mt = 0; mt < 4; mt++) {
            acc[mt][0] = __builtin_amdgcn_mfma_f32_16x16x32_bf16(af[mt], bf0, acc[mt][0], 0, 0, 0);
            acc[mt][1] = __builtin_amdgcn_mfma_f32_16x16x32_bf16(af[mt], bf1, acc[mt][1], 0, 0, 0);
        }
        __builtin_amdgcn_s_setprio(0);
        asm volatile("s_waitcnt vmcnt(2)\n\ts_barrier" ::: "memory");
        bi = (bi == 2) ? 0 : bi + 1;
        si = (si == 2) ? 0 : si + 1;
        st = (st == NT - 1) ? 0 : st + 1;
    }
#undef QSTG

    const int seg = blockIdx.x >> 3;         // 0=Q, 1=K, 2=V (wave-uniform)
    const int bnl = (blockIdx.x & 7) * 128;  // col base within segment
    const float* bias = (seg == 0) ? bq : (seg == 1) ? bk : bv;

    if (seg == 0) {
#pragma unroll
        for (int nt = 0; nt < 2; nt++) {
            const int col = bnl + wc * 32 + nt * 16 + lq;
            const float bvv = bias[col];
            const float sc = LOG2E / (__expf(beta[col >> 6]) * 8.0f);
#pragma unroll
            for (int mt = 0; mt < 4; mt++) {
                const int row = bm + wr * 64 + mt * 16 + lg * 4;
#pragma unroll
                for (int r = 0; r < 4; r++) {
                    float v = (acc[mt][nt][r] + bvv) * sc;
                    Qo[(size_t)(row + r) * DMODEL + col] = (bf16)v;
                }
            }
        }
    } else {
        bf16* out = (seg == 1) ? Kp : Vp;
#pragma unroll
        for (int mt = 0; mt < 4; mt++) {
            const int F   = bm + wr * 64 + mt * 16;
            const int S0X = F >> 2;              // s of (lg=0): s = S0X + lg
            const int T   = S0X >> 4;            // key-tile index s/16
            const int sl  = (S0X & 15) + lg;     // s within tile (S0X%4==0)
#pragma unroll
            for (int nt = 0; nt < 2; nt++) {
                const int col = bnl + wc * 32 + nt * 16 + lq;
                const int h   = col >> 6;
                const int dh  = col & 63;
                const float bvv = bias[col];
#pragma unroll
                for (int r = 0; r < 4; r++) {   // r = batch b
                    float v = acc[mt][nt][r] + bvv;
                    size_t addr;
                    if (seg == 1) {   // Kp: c=dh>>5, u=dh&31
                        addr = ((size_t)((r * 16 + h) * 128 + T)) * 1024
                             + (dh >> 5) * 512
                             + (sl + 16 * ((dh >> 3) & 3)) * 8
                             + (dh & 7);
                    } else {          // Vp: dt=dh>>4
                        addr = ((size_t)((r * 16 + h) * 128 + T)) * 1024
                             + (dh >> 4) * 256 + ((dh & 15) + 16 * (sl >> 2)) * 4
                             + (sl & 3);
                    }
                    out[addr] = (bf16)v;
                }
            }
        }
    }
}

// ---------------------------------------------------------------------------
// R5 output projection: 128x128 tile, 4 waves of 64x64 (acc[4][4]), grid
// (8,64)=512 blocks, 3-buffer LDS 48KB, depth-2 counted vmcnt(4) pipeline,
// launch_bounds(256,3) -> 3 blocks/CU.  FROZEN (matches best-total R7).
// ---------------------------------------------------------------------------
__global__ __launch_bounds__(256, 3) void gemm_out(const bf16* __restrict__ A,
                                                   const bf16* __restrict__ W,
                                                   const float* __restrict__ bias,
                                                   float* __restrict__ C) {
    constexpr int BK = 32;
    constexpr int NTILES = DMODEL / BK;   // 32
    __shared__ __align__(16) bf16 sA[3][128 * BK];   // 24 KB
    __shared__ __align__(16) bf16 sB[3][128 * BK];   // 24 KB

    const int t    = threadIdx.x;
    const int lane = t & 63;
    const int wave = t >> 6;     // 0..3
    const int wr   = wave >> 1;  // 0..1
    const int wc   = wave & 1;   // 0..1
    const int lq   = lane & 15;
    const int lg   = lane >> 4;
    const int bn   = blockIdx.x * 128;
    const int bm   = blockIdx.y * 128;

    const int schunk = (lane & 3) ^ ((lane >> 3) & 3);
    const bf16* ApS = A + (size_t)(bm + wave * 32 + (lane >> 2)) * DMODEL + schunk * 8;
    const bf16* WpS = W + (size_t)(bn + wave * 32 + (lane >> 2)) * DMODEL + schunk * 8;
    const int koff = (lg ^ ((lq >> 1) & 3)) * 8;

    f32x4 acc[4][4] = {};

#define OSTAGE(si_, ko_)                                                                              \
    __builtin_amdgcn_global_load_lds(AS1C(ApS + (ko_)),               AS3(&sA[si_][(wave*32 +  0)*BK]), 16,0,0); \
    __builtin_amdgcn_global_load_lds(AS1C(ApS + 16*DMODEL + (ko_)),   AS3(&sA[si_][(wave*32 + 16)*BK]), 16,0,0); \
    __builtin_amdgcn_global_load_lds(AS1C(WpS + (ko_)),               AS3(&sB[si_][(wave*32 +  0)*BK]), 16,0,0); \
    __builtin_amdgcn_global_load_lds(AS1C(WpS + 16*DMODEL + (ko_)),   AS3(&sB[si_][(wave*32 + 16)*BK]), 16,0,0);

    OSTAGE(0, 0)
    OSTAGE(1, BK)
    asm volatile("s_waitcnt vmcnt(4)\n\ts_barrier" ::: "memory");

    int bi = 0, si = 2, st = 2;
    for (int tt = 0; tt < NTILES; ++tt) {
        OSTAGE(si, (size_t)st * BK)
        const bf16* At = sA[bi];
        const bf16* Bt = sB[bi];
        bf16x8 bfr[4], af[4];
#pragma unroll
        for (int nt = 0; nt < 4; nt++)
            bfr[nt] = *(const bf16x8*)&Bt[(wc * 64 + nt * 16 + lq) * BK + koff];
#pragma unroll
        for (int mt = 0; mt < 4; mt++)
            af[mt] = *(const bf16x8*)&At[(wr * 64 + mt * 16 + lq) * BK + koff];
        __builtin_amdgcn_s_setprio(1);
#pragma unroll
        for (int mt = 0; mt < 4; mt++)
#pragma unroll
            for (int nt = 0; nt < 4; nt++)
                acc[mt][nt] = __builtin_amdgcn_mfma_f32_16x16x32_bf16(af[mt], bfr[nt], acc[mt][nt], 0, 0, 0);
        __builtin_amdgcn_s_setprio(0);
        asm volatile("s_waitcnt vmcnt(4)\n\ts_barrier" ::: "memory");
        bi = (bi == 2) ? 0 : bi + 1;
        si = (si == 2) ? 0 : si + 1;
        st = (st == NTILES - 1) ? 0 : st + 1;
    }
#undef OSTAGE

#pragma unroll
    for (int nt = 0; nt < 4; nt++) {
        const int col = bn + wc * 64 + nt * 16 + lq;
        const float bvv = bias[col];
#pragma unroll
        for (int mt = 0; mt < 4; mt++) {
            const int row = bm + wr * 64 + mt * 16 + lg * 4;
#pragma unroll
            for (int r = 0; r < 4; r++)
                C[(size_t)(row + r) * DMODEL + col] = acc[mt][nt][r] + bvv;
        }
    }
}

// ---------------------------------------------------------------------------
// Flash attention, causal + zero-sink, keys-split waves — measured-best R7
// version (76-78us, Occ 22.9, MfmaUtil 27), REVERTED after R8/R9/R11 all
// regressed by sacrificing one invariant each:
//  (1) 1-deep register prefetch of K/V (R8 dropped it: FETCH +75%, dur +14%);
//  (2) keys-split: each wave loads a DISTINCT tile per iteration so the
//      block streams K/V once (R9 dropped it: 4x L2 traffic, dur 2.2x);
//  (3) paired q-tiles (qi, 31-qi): uniform 33-iter blocks keep the per-XCD
//      L2 window bounded (R11 dropped it: heavy-first spread the live
//      window to ~4MB = L2 size, FETCH 46->105MB, dur 3x);
//  (4) XCD-chunked bijective swizzle.
// The reg-file cap (84 VGPR + 64 AGPR -> 2 blocks/CU) stands: every path
// to more residency breaks (1), (2) or (3).  Local optimum; FROZEN.
// ---------------------------------------------------------------------------
__global__ __launch_bounds__(256, 3) void attn_kernel(const bf16* __restrict__ Q,
                                                      const bf16* __restrict__ Kp,
                                                      const bf16* __restrict__ Vp,
                                                      bf16* __restrict__ O) {
    __shared__ __align__(16) float sO[64 * 65];   // 16640 B (epilogue only)
    __shared__ __align__(16) float sL[256];       // 1024 B

    const int t    = threadIdx.x;
    const int lane = t & 63;
    const int wave = t >> 6;
    const int lq = lane & 15;
    const int lg = lane >> 4;

    // ---- XCD-chunked swizzle (1024 blocks, 8 XCDs, 128 work-ids per XCD) ----
    const int bid = (int)blockIdx.x + 16 * ((int)blockIdx.y + 16 * (int)blockIdx.z);
    const int swz = (bid & 7) * 128 + (bid >> 3);
    const int idx = swz & 15;                     // pair index within slab
    const int h   = (swz >> 4) & 15;
    const int b   = swz >> 8;

    const bf16* Kb = Kp + (size_t)(b * NHEAD + h) * 131072;   // 128 tiles * 1024
    const bf16* Vb = Vp + (size_t)(b * NHEAD + h) * 131072;

#pragma clang loop unroll(disable)
    for (int pass = 0; pass < 2; ++pass) {
        const int qi = (pass == 0) ? (31 - idx) : idx;   // 33 iters total/block
        const int qb = qi * 64;

        // Loop-invariant Q fragments (B-operand of the St MFMA): [n=q][k=dh]
        bf16x8 qf[4][2];
#pragma unroll
        for (int nt = 0; nt < 4; nt++)
#pragma unroll
            for (int kc = 0; kc < 2; kc++)
                qf[nt][kc] = *(const bf16x8*)
                    &Q[((size_t)(qb + nt * 16 + lq) * BATCH + b) * DMODEL + h * DHEAD + kc * 32 + lg * 8];

        f32x4 o_acc[4][4] = {};   // o_acc[dt][nt][r]: O^T row d=dt*16+lg*4+r, col q=nt*16+lq
        float l_lane[4] = {0.f, 0.f, 0.f, 0.f};

        bf16x8 kc0 = *(const bf16x8*)(Kb + (size_t)wave * 1024 + lane * 8);
        bf16x8 kc1 = *(const bf16x8*)(Kb + (size_t)wave * 1024 + 512 + lane * 8);
        bf16x4 vc0 = *(const bf16x4*)(Vb + (size_t)wave * 1024 +   0 + lane * 4);
        bf16x4 vc1 = *(const bf16x4*)(Vb + (size_t)wave * 1024 + 256 + lane * 4);
        bf16x4 vc2 = *(const bf16x4*)(Vb + (size_t)wave * 1024 + 512 + lane * 4);
        bf16x4 vc3 = *(const bf16x4*)(Vb + (size_t)wave * 1024 + 768 + lane * 4);

        for (int kt = 0; kt <= qi; kt++) {
            // prefetch next tile (wraps to tile 0 on last iter, unused)
            const int tn = ((kt < qi) ? (kt + 1) : 0) * 4 + wave;
            const bf16* Kn = Kb + (size_t)tn * 1024;
            const bf16* Vn = Vb + (size_t)tn * 1024;
            bf16x8 kn0 = *(const bf16x8*)(Kn + lane * 8);
            bf16x8 kn1 = *(const bf16x8*)(Kn + 512 + lane * 8);
            bf16x4 vn0 = *(const bf16x4*)(Vn +   0 + lane * 4);
            bf16x4 vn1 = *(const bf16x4*)(Vn + 256 + lane * 4);
            bf16x4 vn2 = *(const bf16x4*)(Vn + 512 + lane * 4);
            bf16x4 vn3 = *(const bf16x4*)(Vn + 768 + lane * 4);

            // St[key][q]: this wave's 16 keys x 64 q  (A = K rows, B = Q rows)
            f32x4 st[4];
            __builtin_amdgcn_s_setprio(1);
#pragma unroll
            for (int nt = 0; nt < 4; nt++) {
                f32x4 a = {};
                a = __builtin_amdgcn_mfma_f32_16x16x32_bf16(kc0, qf[nt][0], a, 0, 0, 0);
                a = __builtin_amdgcn_mfma_f32_16x16x32_bf16(kc1, qf[nt][1], a, 0, 0, 0);
                st[nt] = a;
            }
            __builtin_amdgcn_s_setprio(0);

            // causal mask on the diagonal tile: key_local > q_local -> -inf
            if (kt == qi) {
#pragma unroll
                for (int nt = 0; nt < 4; nt++)
#pragma unroll
                    for (int r = 0; r < 4; r++)
                        if (wave * 16 + lg * 4 + r > nt * 16 + lq) st[nt][r] = -1e30f;
            }

            // P^T = exp2(St) (scores pre-scaled by log2e), pack to bf16, track l
            short4_t pf[4];
#pragma unroll
            for (int nt = 0; nt < 4; nt++) {
                float p0 = __builtin_amdgcn_exp2f(st[nt][0]);
                float p1 = __builtin_amdgcn_exp2f(st[nt][1]);
                float p2 = __builtin_amdgcn_exp2f(st[nt][2]);
                float p3 = __builtin_amdgcn_exp2f(st[nt][3]);
                l_lane[nt] += (p0 + p1) + (p2 + p3);
                bf16x4 pv;
                pv[0] = (bf16)p0; pv[1] = (bf16)p1; pv[2] = (bf16)p2; pv[3] = (bf16)p3;
                pf[nt] = __builtin_bit_cast(short4_t, pv);
            }

            // O^T += Vt(d x key16) * P^T   via mfma_f32_16x16x16_bf16
            short4_t va0 = __builtin_bit_cast(short4_t, vc0);
            short4_t va1 = __builtin_bit_cast(short4_t, vc1);
            short4_t va2 = __builtin_bit_cast(short4_t, vc2);
            short4_t va3 = __builtin_bit_cast(short4_t, vc3);
            __builtin_amdgcn_s_setprio(1);
#pragma unroll
            for (int nt = 0; nt < 4; nt++) {
                o_acc[0][nt] = __builtin_amdgcn_mfma_f32_16x16x16bf16_1k(va0, pf[nt], o_acc[0][nt], 0, 0, 0);
                o_acc[1][nt] = __builtin_amdgcn_mfma_f32_16x16x16bf16_1k(va1, pf[nt], o_acc[1][nt], 0, 0, 0);
                o_acc[2][nt] = __builtin_amdgcn_mfma_f32_16x16x16bf16_1k(va2, pf[nt], o_acc[2][nt], 0, 0, 0);
                o_acc[3][nt] = __builtin_amdgcn_mfma_f32_16x16x16bf16_1k(va3, pf[nt], o_acc[3][nt], 0, 0, 0);
            }
            __builtin_amdgcn_s_setprio(0);

            kc0 = kn0; kc1 = kn1;
            vc0 = vn0; vc1 = vn1; vc2 = vn2; vc3 = vn3;
        }

        // ---------------- epilogue: cross-wave reduction ----------------
#pragma unroll
        for (int nt = 0; nt < 4; nt++) {
            float v = l_lane[nt];
            v += __shfl_xor(v, 16);
            v += __shfl_xor(v, 32);
            if (lg == 0) sL[wave * 64 + nt * 16 + lq] = v;
        }

        // O^T reduction rounds. Round rd: wave w handles slice dt=(w+rd)&3
#pragma unroll
        for (int rd = 0; rd < 4; rd++) {
#pragma unroll
            for (int dtc = 0; dtc < 4; dtc++) {
                if (((wave + rd) & 3) == dtc) {
                    if (rd == 0) {
#pragma unroll
                        for (int nt = 0; nt < 4; nt++)
#pragma unroll
                            for (int r = 0; r < 4; r++)
                                sO[(dtc * 16 + lg * 4 + r) * 65 + nt * 16 + lq] = o_acc[dtc][nt][r];
                    } else {
#pragma unroll
                        for (int nt = 0; nt < 4; nt++)
#pragma unroll
                            for (int r = 0; r < 4; r++)
                                sO[(dtc * 16 + lg * 4 + r) * 65 + nt * 16 + lq] += o_acc[dtc][nt][r];
                    }
                }
            }
            __syncthreads();
        }

        // final: wave stores dt=wave slice of O = O^T / l  (sink adds 1 to l)
        const int dt = wave;
        float rec[4];
#pragma unroll
        for (int nt = 0; nt < 4; nt++) {
            float lt = 1.0f + sL[nt * 16 + lq] + sL[64 + nt * 16 + lq]
                     + sL[128 + nt * 16 + lq] + sL[192 + nt * 16 + lq];
            rec[nt] = 1.0f / lt;
        }
#pragma unroll
        for (int nt = 0; nt < 4; nt++) {
            bf16x4 ov;
#pragma unroll
            for (int r = 0; r < 4; r++)
                ov[r] = (bf16)(sO[(dt * 16 + lg * 4 + r) * 65 + nt * 16 + lq] * rec[nt]);
            *(bf16x4*)&O[((size_t)(qb + nt * 16 + lq) * BATCH + b) * DMODEL + h * DHEAD + dt * 16 + lg * 4] = ov;
        }

        __syncthreads();   // sO/sL reused by next pass
    }
}

// ---------------------------------------------------------------------------
extern "C" void kernel_launch(void* const* d_in, const int* in_sizes, int n_in,
                              void* d_out, int out_size, void* d_ws, size_t ws_size,
                              hipStream_t stream) {
    const float* x    = (const float*)d_in[0];
    // d_in[1] = attn_mask (pure causal -1e9; implemented structurally)
    const float* beta = (const float*)d_in[2];
    const float* Wq   = (const float*)d_in[3];
    const float* bq   = (const float*)d_in[4];
    const float* Wk   = (const float*)d_in[5];
    const float* bk   = (const float*)d_in[6];
    const float* Wv   = (const float*)d_in[7];
    const float* bv   = (const float*)d_in[8];
    const float* Wo   = (const float*)d_in[9];
    const float* bo   = (const float*)d_in[10];
    float* out = (float*)d_out;

    char* ws = (char*)d_ws;
    size_t off = 0;
    auto alloc = [&](size_t bytes) -> void* {
        void* p = ws + off;
        off += (bytes + 255) & ~(size_t)255;
        return p;
    };
    const size_t xbytes = (size_t)MROWS * DMODEL * sizeof(bf16);   // 16 MB
    const size_t wbytes = (size_t)DMODEL * DMODEL * sizeof(bf16);  // 2 MB
    bf16* xb   = (bf16*)alloc(xbytes);
    bf16* wqkv = (bf16*)alloc(3 * wbytes);   // stacked Wq/Wk/Wv
    bf16* wob  = (bf16*)alloc(wbytes);
    bf16* qws  = (bf16*)alloc(xbytes);
    bf16* kpb  = (bf16*)alloc(xbytes);   // packed K
    bf16* vpb  = (bf16*)alloc(xbytes);   // packed V
    bf16* aob  = (bf16*)alloc(xbytes);

    constexpr int NX8 = MROWS * DMODEL / 8;
    constexpr int NW8 = DMODEL * DMODEL / 8;
    cast_all<<<(NX8 + 4 * NW8) / 256, 256, 0, stream>>>(x, Wq, Wk, Wv, Wo, xb, wqkv, wob);

    dim3 qgrid(3 * DMODEL / 128, MROWS / 128);   // (24, 64) = 1536 blocks
    qkv_gemm<<<qgrid, 512, 0, stream>>>(xb, wqkv, bq, bk, bv, beta, qws, kpb, vpb);

    dim3 agrid(S_LEN / 128, NHEAD, BATCH);       // (16, 16, 4) = 1024 blocks
    attn_kernel<<<agrid, 256, 0, stream>>>(qws, kpb, vpb, aob);

    dim3 ogrid(DMODEL / 128, MROWS / 128);       // (8, 64) = 512 blocks
    gemm_out<<<ogrid, 256, 0, stream>>>(aob, wob, bo, out);
}